// Round 5
// baseline (643.656 us; speedup 1.0000x reference)
//
#include <hip/hip_runtime.h>
#include <hip/hip_bf16.h>

#define NN 6144
#define DD 128
#define INV_TAU 10.0f

typedef __attribute__((ext_vector_type(4))) float f32x4;
typedef __attribute__((ext_vector_type(8))) short s16x8;

// ---------------- Kernel 1: L2 normalize rows -> bf16 copies ---------------
__global__ void k_normalize(const float* __restrict__ embF,
                            const float* __restrict__ embM,
                            const float* __restrict__ embP,
                            __hip_bfloat16* __restrict__ Fnb,
                            __hip_bfloat16* __restrict__ Mnb,
                            __hip_bfloat16* __restrict__ Pnb) {
    int which = blockIdx.y;
    const float* src = which == 0 ? embF : (which == 1 ? embM : embP);
    __hip_bfloat16* dstb = which == 0 ? Fnb : (which == 1 ? Mnb : Pnb);
    int wave = threadIdx.x >> 6, lane = threadIdx.x & 63;
    int row = blockIdx.x * 4 + wave;
    float2 v = reinterpret_cast<const float2*>(src + (size_t)row * DD)[lane];
    float s = v.x * v.x + v.y * v.y;
#pragma unroll
    for (int m = 1; m <= 32; m <<= 1) s += __shfl_xor(s, m);
    float inv = 1.0f / fmaxf(sqrtf(s), 1e-12f);
    __hip_bfloat162 ob;
    ob.x = __float2bfloat16(v.x * inv);
    ob.y = __float2bfloat16(v.y * inv);
    reinterpret_cast<__hip_bfloat162*>(dstb + (size_t)row * DD)[lane] = ob;
}

// ------- Kernel 2: dense pass: tot/pos/cnt + nnz index extraction ----------
// grid (96, 8, 2), block 256 = 4 waves, wave = 16 rows x 768-col strip.
// 64-col macro-tiles: adjacency via dwordx4 + 1-iter register double-buffer,
// layout-converted through wave-private LDS. Branch-free extraction.
__global__ __launch_bounds__(256) void k_dense(
        const float* __restrict__ FM_adj, const float* __restrict__ FP_adj,
        const __hip_bfloat16* __restrict__ Fnb,
        const __hip_bfloat16* __restrict__ Mnb,
        const __hip_bfloat16* __restrict__ Pnb,
        float* __restrict__ FMpos, float* __restrict__ FPpos,
        float* __restrict__ FMtot, float* __restrict__ FPtot,
        float* __restrict__ cntF, float* __restrict__ cntP,
        int* __restrict__ nzbuf, int* __restrict__ cntseg) {
    __shared__ float adjS[4][16 * 68];          // stride 68: 2-way banks = free
    const int half = blockIdx.z;
    const float* adj = half ? FP_adj : FM_adj;
    const __hip_bfloat16* Bnb = half ? Pnb : Mnb;
    float* POS = half ? FPpos : FMpos;
    float* TOT = half ? FPtot : FMtot;
    float* CNT = half ? cntP : cntF;
    const int tid = threadIdx.x;
    const int w = tid >> 6, lane = tid & 63;
    const int m = lane & 15, q = lane >> 4;
    const int rb = blockIdx.x * 64 + w * 16;     // wave's 16 rows
    const int by = blockIdx.y;
    const int j0 = by * (NN / 8), jend = j0 + NN / 8;

    float* myS = adjS[w];
    float4* myS4 = reinterpret_cast<float4*>(myS);

    // loop-invariant A fragments: lane holds A[m][k=q*8+j], k-step 32
    s16x8 a[4];
#pragma unroll
    for (int ks = 0; ks < 4; ++ks)
        a[ks] = *reinterpret_cast<const s16x8*>(
            Fnb + (size_t)(rb + m) * DD + ks * 32 + q * 8);

    const float* rowp[4];
    int nzbase[4];
#pragma unroll
    for (int r = 0; r < 4; ++r) {
        rowp[r] = adj + (size_t)(rb + q * 4 + r) * NN;
        nzbase[r] = ((half * NN + rb + q * 4 + r) << 7) + (by << 4);
    }

    float tot[4] = {0.f, 0.f, 0.f, 0.f};
    float pos[4] = {0.f, 0.f, 0.f, 0.f};
    float cnt[4] = {0.f, 0.f, 0.f, 0.f};
    int cnt4[4] = {0, 0, 0, 0};

    // prefetch first adjacency macro-tile (4 x dwordx4 per lane)
    float4 adn[4];
#pragma unroll
    for (int r = 0; r < 4; ++r)
        adn[r] = reinterpret_cast<const float4*>(rowp[r] + j0)[m];

    for (int jc = j0; jc < jend; jc += 64) {
        float4 adc[4];
#pragma unroll
        for (int r = 0; r < 4; ++r) adc[r] = adn[r];
        int jn = (jc + 64 < jend) ? jc + 64 : j0;   // wrap: harmless reload
#pragma unroll
        for (int r = 0; r < 4; ++r)
            adn[r] = reinterpret_cast<const float4*>(rowp[r] + jn)[m];
        // stage current adjacency to LDS (wave-private; no barrier anywhere)
#pragma unroll
        for (int r = 0; r < 4; ++r)
            myS4[(q * 4 + r) * 17 + m] = adc[r];
        // B fragments (L2-resident) + MFMA for 4 tiles
        s16x8 bfr[4][4];
#pragma unroll
        for (int t = 0; t < 4; ++t) {
            const __hip_bfloat16* bp = Bnb + (size_t)(jc + t * 16 + m) * DD + q * 8;
#pragma unroll
            for (int ks = 0; ks < 4; ++ks)
                bfr[t][ks] = *reinterpret_cast<const s16x8*>(bp + ks * 32);
        }
        f32x4 acc[4];
#pragma unroll
        for (int t = 0; t < 4; ++t) {
            acc[t] = (f32x4){0.f, 0.f, 0.f, 0.f};
#pragma unroll
            for (int ks = 0; ks < 4; ++ks)
                acc[t] = __builtin_amdgcn_mfma_f32_16x16x32_bf16(a[ks], bfr[t][ks],
                                                                acc[t], 0, 0, 0);
        }
        // consume: C layout lane(q,m) -> row q*4+r, col jc+t*16+m
#pragma unroll
        for (int t = 0; t < 4; ++t) {
#pragma unroll
            for (int r = 0; r < 4; ++r) {
                float avv = myS[(q * 4 + r) * 68 + t * 16 + m];
                float e = __expf(acc[t][r] * INV_TAU);
                tot[r] += e;
                pos[r] = fmaf(avv, e, pos[r]);     // adj is exactly 0/1
                cnt[r] += avv;
                unsigned long long mask = __ballot(avv != 0.0f);
                unsigned sub = (unsigned)((mask >> (q * 16)) & 0xFFFFu);
                unsigned below = sub & ((1u << m) - 1u);
                int slot = cnt4[r] + __popc(below);
                if (avv != 0.0f && slot < 16)
                    nzbuf[nzbase[r] + slot] = jc + t * 16 + m;
                cnt4[r] += __popc(sub);            // uniform across 16-lane group
            }
        }
    }

    // reduce tot/pos/cnt across the 16 m-lanes sharing each row
#pragma unroll
    for (int msk = 1; msk <= 8; msk <<= 1) {
#pragma unroll
        for (int r = 0; r < 4; ++r) {
            tot[r] += __shfl_xor(tot[r], msk);
            pos[r] += __shfl_xor(pos[r], msk);
            cnt[r] += __shfl_xor(cnt[r], msk);
        }
    }
    if (m == 0) {
#pragma unroll
        for (int r = 0; r < 4; ++r) {
            int row = rb + q * 4 + r;
            atomicAdd(&TOT[row], tot[r]);
            atomicAdd(&POS[row], pos[r]);
            atomicAdd(&CNT[row], cnt[r]);
            cntseg[(half * NN + row) * 8 + by] = cnt4[r] < 16 ? cnt4[r] : 16;
        }
    }
}

// ------- Kernel 3: sparse repr gather -> feat ------------------------------
__global__ void k_gather(const float* __restrict__ embM,
                         const float* __restrict__ embP,
                         const int* __restrict__ nzbuf,
                         const int* __restrict__ cntseg,
                         const float* __restrict__ cntF,
                         const float* __restrict__ cntP,
                         float* __restrict__ feat) {
    __shared__ int listS[128];
    __shared__ int kS[2];
    const int row = blockIdx.x, h = blockIdx.y;
    const int tid = threadIdx.x;              // 0..127 = output dim
    const int wv = tid >> 6, lane = tid & 63;
    const float* embX = h ? embP : embM;
    int seg = tid >> 4;
    int c = cntseg[((size_t)h * NN + row) * 8 + seg];
    bool valid = (tid & 15) < c;
    int j = valid ? nzbuf[(((size_t)h * NN + row) << 7) + tid] : 0;
    unsigned long long mask = __ballot(valid);
    int pref = __popcll(mask & ((1ULL << lane) - 1ULL));
    if (lane == 0) kS[wv] = __popcll(mask);
    __syncthreads();
    int off = (wv ? kS[0] : 0) + pref;
    if (valid) listS[off] = j;
    __syncthreads();
    int K = kS[0] + kS[1];
    // 4-way ILP so >=4 independent loads stay in flight
    float a0 = 0.f, a1 = 0.f, a2 = 0.f, a3 = 0.f;
    int k = 0;
    for (; k + 4 <= K; k += 4) {
        int i0 = listS[k], i1 = listS[k + 1], i2 = listS[k + 2], i3 = listS[k + 3];
        a0 += embX[(size_t)i0 * DD + tid];
        a1 += embX[(size_t)i1 * DD + tid];
        a2 += embX[(size_t)i2 * DD + tid];
        a3 += embX[(size_t)i3 * DD + tid];
    }
    for (; k < K; ++k) a0 += embX[(size_t)listS[k] * DD + tid];
    float acc = (a0 + a1) + (a2 + a3);
    float cn = (h ? cntP : cntF)[row];
    feat[(size_t)row * (2 * DD) + h * DD + tid] = acc / fmaxf(cn, 1.0f);
}

// ------- Kernel 4: MLP hidden + logits (2 rows / 256-thread block) ---------
__global__ void k_mlp1(const float* __restrict__ feat,
                       const float* __restrict__ W1, const float* __restrict__ b1,
                       const float* __restrict__ W2, const float* __restrict__ b2,
                       float* __restrict__ z) {
    __shared__ float featS[2][2 * DD];
    __shared__ float red[4][2];
    const int tid = threadIdx.x;
    const int rr = tid >> 7, d = tid & 127;
    const int wv = tid >> 6, lane = tid & 63;
    const int row0 = blockIdx.x * 2;
    for (int idx = tid; idx < 2 * 2 * DD; idx += 256)
        featS[idx >> 8][idx & 255] = feat[(size_t)(row0 + (idx >> 8)) * (2 * DD) + (idx & 255)];
    __syncthreads();
    float acc = b1[d];
    for (int c = 0; c < 2 * DD; ++c)
        acc = fmaf(featS[rr][c], W1[c * DD + d], acc);
    float h = fmaxf(acc, 0.0f);
    float p0 = h * W2[2 * d], p1 = h * W2[2 * d + 1];
#pragma unroll
    for (int msk = 1; msk <= 32; msk <<= 1) {
        p0 += __shfl_xor(p0, msk);
        p1 += __shfl_xor(p1, msk);
    }
    if (lane == 0) { red[wv][0] = p0; red[wv][1] = p1; }
    __syncthreads();
    if (tid < 2) {
        z[(row0 + tid) * 2 + 0] = red[2 * tid][0] + red[2 * tid + 1][0] + b2[0];
        z[(row0 + tid) * 2 + 1] = red[2 * tid][1] + red[2 * tid + 1][1] + b2[1];
    }
}

// ------- Kernel 5: softmax weights + loss (one atomic per block) -----------
__global__ void k_loss(const float* __restrict__ z,
                       const float* __restrict__ FMpos, const float* __restrict__ FPpos,
                       const float* __restrict__ FMtot, const float* __restrict__ FPtot,
                       const float* __restrict__ cntF, const float* __restrict__ cntP,
                       float* __restrict__ out) {
    __shared__ float red[4];
    const int tid = threadIdx.x;
    const int lane = tid & 63, wv = tid >> 6;
    const int row = blockIdx.x * 256 + tid;
    float z0 = z[row * 2], z1 = z[row * 2 + 1];
    float mx = fmaxf(z0, z1);
    float e0 = expf(z0 - mx), e1 = expf(z1 - mx);
    float inv = 1.0f / (e0 + e1);
    float w0 = e0 * inv, w1 = e1 * inv;
    out[1 + row * 2 + 0] = w0;
    out[1 + row * 2 + 1] = w1;
    float wp = w0 * FMpos[row] + w1 * FPpos[row];
    float wn = w0 * (FMtot[row] - FMpos[row]) + w1 * (FPtot[row] - FPpos[row]);
    float nei = fmaxf(cntF[row] + cntP[row], 1.0f);
    float ratio = wp / (wp + wn) / nei;
    ratio = fmaxf(ratio, 1e-10f);
    float term = -logf(ratio);
#pragma unroll
    for (int msk = 1; msk <= 32; msk <<= 1) term += __shfl_xor(term, msk);
    if (lane == 0) red[wv] = term;
    __syncthreads();
    if (tid == 0)
        atomicAdd(out, (red[0] + red[1] + red[2] + red[3]) * (1.0f / NN));
}

extern "C" void kernel_launch(void* const* d_in, const int* in_sizes, int n_in,
                              void* d_out, int out_size, void* d_ws, size_t ws_size,
                              hipStream_t stream) {
    const float* embF   = (const float*)d_in[0];
    const float* embM   = (const float*)d_in[1];
    const float* embP   = (const float*)d_in[2];
    const float* FM_adj = (const float*)d_in[3];
    const float* FP_adj = (const float*)d_in[4];
    const float* W1     = (const float*)d_in[5];
    const float* b1     = (const float*)d_in[6];
    const float* W2     = (const float*)d_in[7];
    const float* b2     = (const float*)d_in[8];
    float* out = (float*)d_out;

    float* ws = (float*)d_ws;
    float* FMtot = ws;                       // N   (atomic -> zeroed)
    float* FPtot = FMtot + NN;               // N
    float* FMpos = FPtot + NN;               // N
    float* FPpos = FMpos + NN;               // N
    float* cntF  = FPpos + NN;               // N
    float* cntP  = cntF + NN;                // N
    float* feat  = cntP + NN;                // N*2D
    float* zbuf  = feat + (size_t)NN * 2 * DD;   // N*2
    __hip_bfloat16* Fnb = (__hip_bfloat16*)(zbuf + 2 * NN);
    __hip_bfloat16* Mnb = Fnb + (size_t)NN * DD;
    __hip_bfloat16* Pnb = Mnb + (size_t)NN * DD;
    int* nzbuf  = (int*)(Pnb + (size_t)NN * DD);   // 2*N*128 ints
    int* cntseg = nzbuf + 2 * (size_t)NN * 128;    // 2*N*8 ints

    hipMemsetAsync(FMtot, 0, 6 * NN * sizeof(float), stream);
    hipMemsetAsync(d_out, 0, sizeof(float), stream);

    k_normalize<<<dim3(NN / 4, 3), 256, 0, stream>>>(embF, embM, embP,
                                                     Fnb, Mnb, Pnb);
    k_dense<<<dim3(NN / 64, 8, 2), 256, 0, stream>>>(FM_adj, FP_adj,
                                                     Fnb, Mnb, Pnb,
                                                     FMpos, FPpos, FMtot, FPtot,
                                                     cntF, cntP, nzbuf, cntseg);
    k_gather<<<dim3(NN, 2), 128, 0, stream>>>(embM, embP, nzbuf, cntseg,
                                              cntF, cntP, feat);
    k_mlp1<<<dim3(NN / 2), 256, 0, stream>>>(feat, W1, b1, W2, b2, zbuf);
    k_loss<<<dim3(NN / 256), 256, 0, stream>>>(zbuf, FMpos, FPpos, FMtot, FPtot,
                                               cntF, cntP, out);
}

// Round 6
// 568.804 us; speedup vs baseline: 1.1316x; 1.1316x over previous
//
#include <hip/hip_runtime.h>
#include <hip/hip_bf16.h>

#define NN 6144
#define DD 128
#define INV_TAU 10.0f

typedef __attribute__((ext_vector_type(4))) float f32x4;
typedef __attribute__((ext_vector_type(8))) short s16x8;

// ---------------- Kernel 1: L2 normalize -> fp32 + bf16 copies -------------
__global__ void k_normalize(const float* __restrict__ embF,
                            const float* __restrict__ embM,
                            const float* __restrict__ embP,
                            float* __restrict__ Fn, float* __restrict__ Mn,
                            float* __restrict__ Pn,
                            __hip_bfloat16* __restrict__ Fnb,
                            __hip_bfloat16* __restrict__ Mnb,
                            __hip_bfloat16* __restrict__ Pnb) {
    int which = blockIdx.y;
    const float* src = which == 0 ? embF : (which == 1 ? embM : embP);
    float* dst = which == 0 ? Fn : (which == 1 ? Mn : Pn);
    __hip_bfloat16* dstb = which == 0 ? Fnb : (which == 1 ? Mnb : Pnb);
    int wave = threadIdx.x >> 6, lane = threadIdx.x & 63;
    int row = blockIdx.x * 4 + wave;
    float2 v = reinterpret_cast<const float2*>(src + (size_t)row * DD)[lane];
    float s = v.x * v.x + v.y * v.y;
#pragma unroll
    for (int m = 1; m <= 32; m <<= 1) s += __shfl_xor(s, m);
    float inv = 1.0f / fmaxf(sqrtf(s), 1e-12f);
    float2 o; o.x = v.x * inv; o.y = v.y * inv;
    reinterpret_cast<float2*>(dst + (size_t)row * DD)[lane] = o;
    __hip_bfloat162 ob;
    ob.x = __float2bfloat16(o.x);
    ob.y = __float2bfloat16(o.y);
    reinterpret_cast<__hip_bfloat162*>(dstb + (size_t)row * DD)[lane] = ob;
}

// ------- Kernel 2: adjacency stream -> compact nnz lists + counts ----------
// One wave per (row, half). Pure float4 stream + ballot/mbcnt compaction.
// No LDS, no barriers: nothing blocks load pipelining.
__global__ __launch_bounds__(256) void k_scan(
        const float* __restrict__ FM_adj, const float* __restrict__ FP_adj,
        int* __restrict__ nzbuf, int* __restrict__ nzcnt,
        float* __restrict__ cntF, float* __restrict__ cntP) {
    const int h = blockIdx.y;
    const float* adj = h ? FP_adj : FM_adj;
    const int w = threadIdx.x >> 6, lane = threadIdx.x & 63;
    const int row = blockIdx.x * 4 + w;
    const float4* rp = reinterpret_cast<const float4*>(adj + (size_t)row * NN);
    const int base = (h * NN + row) << 7;
    int total = 0;
#pragma unroll 2
    for (int chunk = 0; chunk < NN / 256; ++chunk) {
        float4 v = rp[chunk * 64 + lane];
        int colbase = chunk * 256 + lane * 4;
        float vals[4] = {v.x, v.y, v.z, v.w};
#pragma unroll
        for (int c = 0; c < 4; ++c) {
            bool nz = vals[c] != 0.0f;
            unsigned long long mask = __ballot(nz);
            int pref = __builtin_amdgcn_mbcnt_hi(
                (unsigned)(mask >> 32),
                __builtin_amdgcn_mbcnt_lo((unsigned)mask, 0));
            int slot = total + pref;
            if (nz && slot < 128) nzbuf[base + slot] = colbase + c;
            total += __popcll(mask);
        }
    }
    if (lane == 0) {
        nzcnt[h * NN + row] = total < 128 ? total : 128;
        (h ? cntP : cntF)[row] = (float)total;
    }
}

// ------- Kernel 3: dense exp row-sum (tot only) via bf16 MFMA --------------
// grid (96, 8, 2), block 256 = 4 waves; wave = 16 rows x 768-col strip.
// Loop body: B loads -> MFMA -> exp -> add. No adjacency, no LDS, no ballot.
__global__ __launch_bounds__(256, 4) void k_dense(
        const __hip_bfloat16* __restrict__ Fnb,
        const __hip_bfloat16* __restrict__ Mnb,
        const __hip_bfloat16* __restrict__ Pnb,
        float* __restrict__ FMtot, float* __restrict__ FPtot) {
    const int half = blockIdx.z;
    const __hip_bfloat16* Bnb = half ? Pnb : Mnb;
    float* TOT = half ? FPtot : FMtot;
    const int tid = threadIdx.x;
    const int w = tid >> 6, lane = tid & 63;
    const int m = lane & 15, q = lane >> 4;
    const int rb = blockIdx.x * 64 + w * 16;
    const int j0 = blockIdx.y * (NN / 8);

    // loop-invariant A fragments: lane holds A[m][k=q*8+j], k-step 32
    s16x8 a[4];
#pragma unroll
    for (int ks = 0; ks < 4; ++ks)
        a[ks] = *reinterpret_cast<const s16x8*>(
            Fnb + (size_t)(rb + m) * DD + ks * 32 + q * 8);

    float tot[4] = {0.f, 0.f, 0.f, 0.f};
    for (int jc = j0; jc < j0 + NN / 8; jc += 32) {
        s16x8 bfr[2][4];
#pragma unroll
        for (int t = 0; t < 2; ++t) {
            const __hip_bfloat16* bp = Bnb + (size_t)(jc + t * 16 + m) * DD + q * 8;
#pragma unroll
            for (int ks = 0; ks < 4; ++ks)
                bfr[t][ks] = *reinterpret_cast<const s16x8*>(bp + ks * 32);
        }
        f32x4 acc[2];
#pragma unroll
        for (int t = 0; t < 2; ++t) {
            acc[t] = (f32x4){0.f, 0.f, 0.f, 0.f};
#pragma unroll
            for (int ks = 0; ks < 4; ++ks)
                acc[t] = __builtin_amdgcn_mfma_f32_16x16x32_bf16(a[ks], bfr[t][ks],
                                                                acc[t], 0, 0, 0);
        }
#pragma unroll
        for (int t = 0; t < 2; ++t)
#pragma unroll
            for (int r = 0; r < 4; ++r)
                tot[r] += __expf(acc[t][r] * INV_TAU);
    }
#pragma unroll
    for (int msk = 1; msk <= 8; msk <<= 1)
#pragma unroll
        for (int r = 0; r < 4; ++r) tot[r] += __shfl_xor(tot[r], msk);
    if (m == 0)
#pragma unroll
        for (int r = 0; r < 4; ++r)
            atomicAdd(&TOT[rb + q * 4 + r], tot[r]);
}

// ------- Kernel 4: gather repr (raw emb) + exact fp32 pos ------------------
// One 128-thread block per (row, half); ~31 indices from k_scan.
__global__ void k_gather(const float* __restrict__ embM,
                         const float* __restrict__ embP,
                         const float* __restrict__ Fn,
                         const float* __restrict__ Mn,
                         const float* __restrict__ Pn,
                         const int* __restrict__ nzbuf,
                         const int* __restrict__ nzcnt,
                         const float* __restrict__ cntF,
                         const float* __restrict__ cntP,
                         float* __restrict__ feat,
                         float* __restrict__ FMpos, float* __restrict__ FPpos) {
    __shared__ float FnS[DD];
    __shared__ int listS[128];
    __shared__ float posS[2];
    const int row = blockIdx.x, h = blockIdx.y;
    const int tid = threadIdx.x;            // 0..127 = output dim
    const int wv = tid >> 6, lane = tid & 63;
    const float* embX = h ? embP : embM;
    const float* Bn = h ? Pn : Mn;
    FnS[tid] = Fn[(size_t)row * DD + tid];
    int K = nzcnt[h * NN + row];
    if (tid < K) listS[tid] = nzbuf[((h * NN + row) << 7) + tid];
    __syncthreads();
    // repr: 4-way ILP
    float a0 = 0.f, a1 = 0.f, a2 = 0.f, a3 = 0.f;
    int k = 0;
    for (; k + 4 <= K; k += 4) {
        int i0 = listS[k], i1 = listS[k + 1], i2 = listS[k + 2], i3 = listS[k + 3];
        a0 += embX[(size_t)i0 * DD + tid];
        a1 += embX[(size_t)i1 * DD + tid];
        a2 += embX[(size_t)i2 * DD + tid];
        a3 += embX[(size_t)i3 * DD + tid];
    }
    for (; k < K; ++k) a0 += embX[(size_t)listS[k] * DD + tid];
    float cn = (h ? cntP : cntF)[row];
    feat[(size_t)row * (2 * DD) + h * DD + tid] =
        ((a0 + a1) + (a2 + a3)) / fmaxf(cn, 1.0f);
    // pos: wave-cooperative fp32 dot + exp per neighbor
    float wsum = 0.f;
    for (int kk = wv; kk < K; kk += 2) {
        int j = listS[kk];
        float2 b = reinterpret_cast<const float2*>(Bn + (size_t)j * DD)[lane];
        float2 f = reinterpret_cast<const float2*>(FnS)[lane];
        float d = f.x * b.x + f.y * b.y;
#pragma unroll
        for (int msk = 1; msk <= 32; msk <<= 1) d += __shfl_xor(d, msk);
        wsum += __expf(d * INV_TAU);
    }
    if (lane == 0) posS[wv] = wsum;
    __syncthreads();
    if (tid == 0) (h ? FPpos : FMpos)[row] = posS[0] + posS[1];
}

// ------- Kernel 5: MLP hidden + logits (2 rows / 256-thread block) ---------
__global__ void k_mlp1(const float* __restrict__ feat,
                       const float* __restrict__ W1, const float* __restrict__ b1,
                       const float* __restrict__ W2, const float* __restrict__ b2,
                       float* __restrict__ z) {
    __shared__ float featS[2][2 * DD];
    __shared__ float red[4][2];
    const int tid = threadIdx.x;
    const int rr = tid >> 7, d = tid & 127;
    const int wv = tid >> 6, lane = tid & 63;
    const int row0 = blockIdx.x * 2;
    for (int idx = tid; idx < 2 * 2 * DD; idx += 256)
        featS[idx >> 8][idx & 255] =
            feat[(size_t)(row0 + (idx >> 8)) * (2 * DD) + (idx & 255)];
    __syncthreads();
    float acc = b1[d];
#pragma unroll 4
    for (int c = 0; c < 2 * DD; ++c)
        acc = fmaf(featS[rr][c], W1[c * DD + d], acc);
    float h = fmaxf(acc, 0.0f);
    float p0 = h * W2[2 * d], p1 = h * W2[2 * d + 1];
#pragma unroll
    for (int msk = 1; msk <= 32; msk <<= 1) {
        p0 += __shfl_xor(p0, msk);
        p1 += __shfl_xor(p1, msk);
    }
    if (lane == 0) { red[wv][0] = p0; red[wv][1] = p1; }
    __syncthreads();
    if (tid < 2) {
        z[(row0 + tid) * 2 + 0] = red[2 * tid][0] + red[2 * tid + 1][0] + b2[0];
        z[(row0 + tid) * 2 + 1] = red[2 * tid][1] + red[2 * tid + 1][1] + b2[1];
    }
}

// ------- Kernel 6: softmax weights + loss (one atomic per block) -----------
__global__ void k_loss(const float* __restrict__ z,
                       const float* __restrict__ FMpos, const float* __restrict__ FPpos,
                       const float* __restrict__ FMtot, const float* __restrict__ FPtot,
                       const float* __restrict__ cntF, const float* __restrict__ cntP,
                       float* __restrict__ out) {
    __shared__ float red[4];
    const int tid = threadIdx.x;
    const int lane = tid & 63, wv = tid >> 6;
    const int row = blockIdx.x * 256 + tid;
    float z0 = z[row * 2], z1 = z[row * 2 + 1];
    float mx = fmaxf(z0, z1);
    float e0 = expf(z0 - mx), e1 = expf(z1 - mx);
    float inv = 1.0f / (e0 + e1);
    float w0 = e0 * inv, w1 = e1 * inv;
    out[1 + row * 2 + 0] = w0;
    out[1 + row * 2 + 1] = w1;
    float wp = w0 * FMpos[row] + w1 * FPpos[row];
    float wn = w0 * (FMtot[row] - FMpos[row]) + w1 * (FPtot[row] - FPpos[row]);
    float nei = fmaxf(cntF[row] + cntP[row], 1.0f);
    float ratio = wp / (wp + wn) / nei;
    ratio = fmaxf(ratio, 1e-10f);
    float term = -logf(ratio);
#pragma unroll
    for (int msk = 1; msk <= 32; msk <<= 1) term += __shfl_xor(term, msk);
    if (lane == 0) red[wv] = term;
    __syncthreads();
    if (tid == 0)
        atomicAdd(out, (red[0] + red[1] + red[2] + red[3]) * (1.0f / NN));
}

extern "C" void kernel_launch(void* const* d_in, const int* in_sizes, int n_in,
                              void* d_out, int out_size, void* d_ws, size_t ws_size,
                              hipStream_t stream) {
    const float* embF   = (const float*)d_in[0];
    const float* embM   = (const float*)d_in[1];
    const float* embP   = (const float*)d_in[2];
    const float* FM_adj = (const float*)d_in[3];
    const float* FP_adj = (const float*)d_in[4];
    const float* W1     = (const float*)d_in[5];
    const float* b1     = (const float*)d_in[6];
    const float* W2     = (const float*)d_in[7];
    const float* b2     = (const float*)d_in[8];
    float* out = (float*)d_out;

    float* ws = (float*)d_ws;
    float* FMtot = ws;                       // N  (atomic -> zeroed)
    float* FPtot = FMtot + NN;               // N  (atomic -> zeroed)
    float* FMpos = FPtot + NN;               // N
    float* FPpos = FMpos + NN;               // N
    float* cntF  = FPpos + NN;               // N
    float* cntP  = cntF + NN;                // N
    float* feat  = cntP + NN;                // N*2D
    float* zbuf  = feat + (size_t)NN * 2 * DD;   // N*2
    float* Fn    = zbuf + 2 * NN;            // N*D fp32 normalized
    float* Mn    = Fn + (size_t)NN * DD;
    float* Pn    = Mn + (size_t)NN * DD;
    __hip_bfloat16* Fnb = (__hip_bfloat16*)(Pn + (size_t)NN * DD);
    __hip_bfloat16* Mnb = Fnb + (size_t)NN * DD;
    __hip_bfloat16* Pnb = Mnb + (size_t)NN * DD;
    int* nzbuf = (int*)(Pnb + (size_t)NN * DD);  // 2*N*128 ints
    int* nzcnt = nzbuf + 2 * (size_t)NN * 128;   // 2*N ints

    hipMemsetAsync(FMtot, 0, 2 * NN * sizeof(float), stream);
    hipMemsetAsync(d_out, 0, sizeof(float), stream);

    k_normalize<<<dim3(NN / 4, 3), 256, 0, stream>>>(embF, embM, embP,
                                                     Fn, Mn, Pn, Fnb, Mnb, Pnb);
    k_scan<<<dim3(NN / 4, 2), 256, 0, stream>>>(FM_adj, FP_adj,
                                                nzbuf, nzcnt, cntF, cntP);
    k_dense<<<dim3(NN / 64, 8, 2), 256, 0, stream>>>(Fnb, Mnb, Pnb, FMtot, FPtot);
    k_gather<<<dim3(NN, 2), 128, 0, stream>>>(embM, embP, Fn, Mn, Pn,
                                              nzbuf, nzcnt, cntF, cntP,
                                              feat, FMpos, FPpos);
    k_mlp1<<<dim3(NN / 2), 256, 0, stream>>>(feat, W1, b1, W2, b2, zbuf);
    k_loss<<<dim3(NN / 256), 256, 0, stream>>>(zbuf, FMpos, FPpos, FMtot, FPtot,
                                               cntF, cntP, out);
}

// Round 7
// 498.355 us; speedup vs baseline: 1.2916x; 1.1414x over previous
//
#include <hip/hip_runtime.h>
#include <hip/hip_bf16.h>

#define NN 6144
#define DD 128
#define INV_TAU 10.0f

typedef __attribute__((ext_vector_type(4))) float f32x4;
typedef __attribute__((ext_vector_type(8))) short s16x8;

// ---------------- Kernel 1: L2 normalize -> fp32 + bf16 copies -------------
__global__ void k_normalize(const float* __restrict__ embF,
                            const float* __restrict__ embM,
                            const float* __restrict__ embP,
                            float* __restrict__ Fn, float* __restrict__ Mn,
                            float* __restrict__ Pn,
                            __hip_bfloat16* __restrict__ Fnb,
                            __hip_bfloat16* __restrict__ Mnb,
                            __hip_bfloat16* __restrict__ Pnb) {
    int which = blockIdx.y;
    const float* src = which == 0 ? embF : (which == 1 ? embM : embP);
    float* dst = which == 0 ? Fn : (which == 1 ? Mn : Pn);
    __hip_bfloat16* dstb = which == 0 ? Fnb : (which == 1 ? Mnb : Pnb);
    int wave = threadIdx.x >> 6, lane = threadIdx.x & 63;
    int row = blockIdx.x * 4 + wave;
    float2 v = reinterpret_cast<const float2*>(src + (size_t)row * DD)[lane];
    float s = v.x * v.x + v.y * v.y;
#pragma unroll
    for (int m = 1; m <= 32; m <<= 1) s += __shfl_xor(s, m);
    float inv = 1.0f / fmaxf(sqrtf(s), 1e-12f);
    float2 o; o.x = v.x * inv; o.y = v.y * inv;
    reinterpret_cast<float2*>(dst + (size_t)row * DD)[lane] = o;
    __hip_bfloat162 ob;
    ob.x = __float2bfloat16(o.x);
    ob.y = __float2bfloat16(o.y);
    reinterpret_cast<__hip_bfloat162*>(dstb + (size_t)row * DD)[lane] = ob;
}

// ------- Kernel 2: adjacency stream -> compact nnz lists + counts ----------
// One wave per (row, half). NO cross-lane ops in the loop: nnz indices go to
// a per-lane LDS side buffer; one prefix-sum at the end compacts them.
__global__ __launch_bounds__(256) void k_scan(
        const float* __restrict__ FM_adj, const float* __restrict__ FP_adj,
        int* __restrict__ nzbuf, int* __restrict__ nzcnt,
        float* __restrict__ cntF, float* __restrict__ cntP) {
    __shared__ int lbuf[4][64 * 12];                 // 12 KB
    const int h = blockIdx.y;
    const float* adj = h ? FP_adj : FM_adj;
    const int w = threadIdx.x >> 6, lane = threadIdx.x & 63;
    const int row = blockIdx.x * 4 + w;
    const float4* rp = reinterpret_cast<const float4*>(adj + (size_t)row * NN);
    int* mybuf = &lbuf[w][lane * 12];
    int mycnt = 0;
#pragma unroll 4
    for (int chunk = 0; chunk < NN / 256; ++chunk) {
        float4 v = rp[chunk * 64 + lane];
        int colbase = chunk * 256 + lane * 4;
        if (v.x != 0.f) { if (mycnt < 12) mybuf[mycnt] = colbase;     mycnt++; }
        if (v.y != 0.f) { if (mycnt < 12) mybuf[mycnt] = colbase + 1; mycnt++; }
        if (v.z != 0.f) { if (mycnt < 12) mybuf[mycnt] = colbase + 2; mycnt++; }
        if (v.w != 0.f) { if (mycnt < 12) mybuf[mycnt] = colbase + 3; mycnt++; }
    }
    int cnt = mycnt < 12 ? mycnt : 12;               // P(lane>12 nnz) ~ 0
    // exclusive prefix over 64 lanes
    int x = cnt;
#pragma unroll
    for (int d = 1; d < 64; d <<= 1) {
        int y = __shfl_up(x, d);
        if (lane >= d) x += y;
    }
    int pref = x - cnt;
    int totc = __shfl(x, 63);
    int t = mycnt;                                   // true row count
#pragma unroll
    for (int msk = 1; msk <= 32; msk <<= 1) t += __shfl_xor(t, msk);
    const int base = (h * NN + row) << 7;
    for (int i = 0; i < cnt; ++i) {
        int slot = pref + i;
        if (slot < 128) nzbuf[base + slot] = mybuf[i];
    }
    if (lane == 0) {
        nzcnt[h * NN + row] = totc < 128 ? totc : 128;
        (h ? cntP : cntF)[row] = (float)t;
    }
}

// ------- Kernel 3: dense exp row-sum via bf16 MFMA, LDS-staged B -----------
// grid (96, 8, 2), block 256 = 4 waves (64 rows); all waves share the same
// j-strip, so the 32-col B tile is staged ONCE into LDS per block.
__global__ __launch_bounds__(256) void k_dense(
        const __hip_bfloat16* __restrict__ Fnb,
        const __hip_bfloat16* __restrict__ Mnb,
        const __hip_bfloat16* __restrict__ Pnb,
        float* __restrict__ FMtot, float* __restrict__ FPtot) {
    __shared__ __hip_bfloat16 Bs[32 * DD];          // 8 KB: 32 rows x 128 dims
    const int half = blockIdx.z;
    const __hip_bfloat16* Bnb = half ? Pnb : Mnb;
    float* TOT = half ? FPtot : FMtot;
    const int tid = threadIdx.x;
    const int w = tid >> 6, lane = tid & 63;
    const int m = lane & 15, q = lane >> 4;
    const int rb = blockIdx.x * 64 + w * 16;
    const int j0 = blockIdx.y * (NN / 8);

    // loop-invariant A fragments: lane holds A[m][k=q*8+j], k-step 32
    s16x8 a[4];
#pragma unroll
    for (int ks = 0; ks < 4; ++ks)
        a[ks] = *reinterpret_cast<const s16x8*>(
            Fnb + (size_t)(rb + m) * DD + ks * 32 + q * 8);

    float4* Bs4 = reinterpret_cast<float4*>(Bs);
    float tot[4] = {0.f, 0.f, 0.f, 0.f};
    for (int jc = j0; jc < j0 + NN / 8; jc += 32) {
        // stage B rows jc..jc+31 (8 KB contiguous) cooperatively
        const float4* gt = reinterpret_cast<const float4*>(Bnb + (size_t)jc * DD);
        float4 s0 = gt[tid], s1 = gt[256 + tid];
        __syncthreads();                  // previous tile fully consumed
        Bs4[tid] = s0;
        Bs4[256 + tid] = s1;
        __syncthreads();                  // tile visible to all waves
        // fragments from LDS + MFMA
#pragma unroll
        for (int t = 0; t < 2; ++t) {
            f32x4 acc = {0.f, 0.f, 0.f, 0.f};
#pragma unroll
            for (int ks = 0; ks < 4; ++ks) {
                s16x8 b = *reinterpret_cast<const s16x8*>(
                    &Bs[(t * 16 + m) * DD + ks * 32 + q * 8]);
                acc = __builtin_amdgcn_mfma_f32_16x16x32_bf16(a[ks], b, acc, 0, 0, 0);
            }
#pragma unroll
            for (int r = 0; r < 4; ++r)
                tot[r] += __expf(acc[r] * INV_TAU);
        }
    }
#pragma unroll
    for (int msk = 1; msk <= 8; msk <<= 1)
#pragma unroll
        for (int r = 0; r < 4; ++r) tot[r] += __shfl_xor(tot[r], msk);
    if (m == 0)
#pragma unroll
        for (int r = 0; r < 4; ++r)
            atomicAdd(&TOT[rb + q * 4 + r], tot[r]);
}

// ------- Kernel 4: gather repr (raw emb) + exact fp32 pos ------------------
__global__ void k_gather(const float* __restrict__ embM,
                         const float* __restrict__ embP,
                         const float* __restrict__ Fn,
                         const float* __restrict__ Mn,
                         const float* __restrict__ Pn,
                         const int* __restrict__ nzbuf,
                         const int* __restrict__ nzcnt,
                         const float* __restrict__ cntF,
                         const float* __restrict__ cntP,
                         float* __restrict__ feat,
                         float* __restrict__ FMpos, float* __restrict__ FPpos) {
    __shared__ float FnS[DD];
    __shared__ int listS[128];
    __shared__ float posS[2];
    const int row = blockIdx.x, h = blockIdx.y;
    const int tid = threadIdx.x;            // 0..127 = output dim
    const int wv = tid >> 6, lane = tid & 63;
    const float* embX = h ? embP : embM;
    const float* Bn = h ? Pn : Mn;
    FnS[tid] = Fn[(size_t)row * DD + tid];
    int K = nzcnt[h * NN + row];
    if (tid < K) listS[tid] = nzbuf[((h * NN + row) << 7) + tid];
    __syncthreads();
    // repr: 4-way ILP
    float a0 = 0.f, a1 = 0.f, a2 = 0.f, a3 = 0.f;
    int k = 0;
    for (; k + 4 <= K; k += 4) {
        int i0 = listS[k], i1 = listS[k + 1], i2 = listS[k + 2], i3 = listS[k + 3];
        a0 += embX[(size_t)i0 * DD + tid];
        a1 += embX[(size_t)i1 * DD + tid];
        a2 += embX[(size_t)i2 * DD + tid];
        a3 += embX[(size_t)i3 * DD + tid];
    }
    for (; k < K; ++k) a0 += embX[(size_t)listS[k] * DD + tid];
    float cn = (h ? cntP : cntF)[row];
    feat[(size_t)row * (2 * DD) + h * DD + tid] =
        ((a0 + a1) + (a2 + a3)) / fmaxf(cn, 1.0f);
    // pos: wave-cooperative fp32 dot + exp per neighbor
    float2 f = reinterpret_cast<const float2*>(FnS)[lane];
    float wsum = 0.f;
    for (int kk = wv; kk < K; kk += 2) {
        int j = listS[kk];
        float2 b = reinterpret_cast<const float2*>(Bn + (size_t)j * DD)[lane];
        float d = f.x * b.x + f.y * b.y;
#pragma unroll
        for (int msk = 1; msk <= 32; msk <<= 1) d += __shfl_xor(d, msk);
        wsum += __expf(d * INV_TAU);
    }
    if (lane == 0) posS[wv] = wsum;
    __syncthreads();
    if (tid == 0) (h ? FPpos : FMpos)[row] = posS[0] + posS[1];
}

// ------- Kernel 5: MLP hidden + logits (8 rows / 256-thread block) ---------
// Thread-group g (128 threads) handles 4 rows with 4 independent acc chains.
__global__ __launch_bounds__(256) void k_mlp1(
        const float* __restrict__ feat,
        const float* __restrict__ W1, const float* __restrict__ b1,
        const float* __restrict__ W2, const float* __restrict__ b2,
        float* __restrict__ z) {
    __shared__ float featS[8][2 * DD];              // 8 KB
    __shared__ float red[4][4][2];
    const int tid = threadIdx.x;
    const int g = tid >> 7, d = tid & 127;
    const int wv = tid >> 6, lane = tid & 63;
    const int row0 = blockIdx.x * 8;
    for (int idx = tid; idx < 8 * 2 * DD; idx += 256)
        featS[idx >> 8][idx & 255] = feat[(size_t)row0 * (2 * DD) + idx];
    __syncthreads();
    float bb = b1[d];
    float acc0 = bb, acc1 = bb, acc2 = bb, acc3 = bb;
    const float* fS = &featS[g * 4][0];
#pragma unroll 4
    for (int c = 0; c < 2 * DD; ++c) {
        float w1v = W1[c * DD + d];
        acc0 = fmaf(fS[0 * 256 + c], w1v, acc0);
        acc1 = fmaf(fS[1 * 256 + c], w1v, acc1);
        acc2 = fmaf(fS[2 * 256 + c], w1v, acc2);
        acc3 = fmaf(fS[3 * 256 + c], w1v, acc3);
    }
    float w20 = W2[2 * d], w21 = W2[2 * d + 1];
    float hr[4] = {fmaxf(acc0, 0.f), fmaxf(acc1, 0.f),
                   fmaxf(acc2, 0.f), fmaxf(acc3, 0.f)};
#pragma unroll
    for (int r = 0; r < 4; ++r) {
        float p0 = hr[r] * w20, p1 = hr[r] * w21;
#pragma unroll
        for (int msk = 1; msk <= 32; msk <<= 1) {
            p0 += __shfl_xor(p0, msk);
            p1 += __shfl_xor(p1, msk);
        }
        if (lane == 0) { red[wv][r][0] = p0; red[wv][r][1] = p1; }
    }
    __syncthreads();
    if (tid < 8) {
        int g2 = tid >> 2, r = tid & 3;
        float z0 = red[2 * g2][r][0] + red[2 * g2 + 1][r][0] + b2[0];
        float z1 = red[2 * g2][r][1] + red[2 * g2 + 1][r][1] + b2[1];
        z[(row0 + tid) * 2 + 0] = z0;
        z[(row0 + tid) * 2 + 1] = z1;
    }
}

// ------- Kernel 6: softmax weights + loss (one atomic per block) -----------
__global__ void k_loss(const float* __restrict__ z,
                       const float* __restrict__ FMpos, const float* __restrict__ FPpos,
                       const float* __restrict__ FMtot, const float* __restrict__ FPtot,
                       const float* __restrict__ cntF, const float* __restrict__ cntP,
                       float* __restrict__ out) {
    __shared__ float red[4];
    const int tid = threadIdx.x;
    const int lane = tid & 63, wv = tid >> 6;
    const int row = blockIdx.x * 256 + tid;
    float z0 = z[row * 2], z1 = z[row * 2 + 1];
    float mx = fmaxf(z0, z1);
    float e0 = expf(z0 - mx), e1 = expf(z1 - mx);
    float inv = 1.0f / (e0 + e1);
    float w0 = e0 * inv, w1 = e1 * inv;
    out[1 + row * 2 + 0] = w0;
    out[1 + row * 2 + 1] = w1;
    float wp = w0 * FMpos[row] + w1 * FPpos[row];
    float wn = w0 * (FMtot[row] - FMpos[row]) + w1 * (FPtot[row] - FPpos[row]);
    float nei = fmaxf(cntF[row] + cntP[row], 1.0f);
    float ratio = wp / (wp + wn) / nei;
    ratio = fmaxf(ratio, 1e-10f);
    float term = -logf(ratio);
#pragma unroll
    for (int msk = 1; msk <= 32; msk <<= 1) term += __shfl_xor(term, msk);
    if (lane == 0) red[wv] = term;
    __syncthreads();
    if (tid == 0)
        atomicAdd(out, (red[0] + red[1] + red[2] + red[3]) * (1.0f / NN));
}

extern "C" void kernel_launch(void* const* d_in, const int* in_sizes, int n_in,
                              void* d_out, int out_size, void* d_ws, size_t ws_size,
                              hipStream_t stream) {
    const float* embF   = (const float*)d_in[0];
    const float* embM   = (const float*)d_in[1];
    const float* embP   = (const float*)d_in[2];
    const float* FM_adj = (const float*)d_in[3];
    const float* FP_adj = (const float*)d_in[4];
    const float* W1     = (const float*)d_in[5];
    const float* b1     = (const float*)d_in[6];
    const float* W2     = (const float*)d_in[7];
    const float* b2     = (const float*)d_in[8];
    float* out = (float*)d_out;

    float* ws = (float*)d_ws;
    float* FMtot = ws;                       // N  (atomic -> zeroed)
    float* FPtot = FMtot + NN;               // N  (atomic -> zeroed)
    float* FMpos = FPtot + NN;               // N
    float* FPpos = FMpos + NN;               // N
    float* cntF  = FPpos + NN;               // N
    float* cntP  = cntF + NN;                // N
    float* feat  = cntP + NN;                // N*2D
    float* zbuf  = feat + (size_t)NN * 2 * DD;   // N*2
    float* Fn    = zbuf + 2 * NN;            // N*D fp32 normalized
    float* Mn    = Fn + (size_t)NN * DD;
    float* Pn    = Mn + (size_t)NN * DD;
    __hip_bfloat16* Fnb = (__hip_bfloat16*)(Pn + (size_t)NN * DD);
    __hip_bfloat16* Mnb = Fnb + (size_t)NN * DD;
    __hip_bfloat16* Pnb = Mnb + (size_t)NN * DD;
    int* nzbuf = (int*)(Pnb + (size_t)NN * DD);  // 2*N*128 ints
    int* nzcnt = nzbuf + 2 * (size_t)NN * 128;   // 2*N ints

    hipMemsetAsync(FMtot, 0, 2 * NN * sizeof(float), stream);
    hipMemsetAsync(d_out, 0, sizeof(float), stream);

    k_normalize<<<dim3(NN / 4, 3), 256, 0, stream>>>(embF, embM, embP,
                                                     Fn, Mn, Pn, Fnb, Mnb, Pnb);
    k_scan<<<dim3(NN / 4, 2), 256, 0, stream>>>(FM_adj, FP_adj,
                                                nzbuf, nzcnt, cntF, cntP);
    k_dense<<<dim3(NN / 64, 8, 2), 256, 0, stream>>>(Fnb, Mnb, Pnb, FMtot, FPtot);
    k_gather<<<dim3(NN, 2), 128, 0, stream>>>(embM, embP, Fn, Mn, Pn,
                                              nzbuf, nzcnt, cntF, cntP,
                                              feat, FMpos, FPpos);
    k_mlp1<<<dim3(NN / 8), 256, 0, stream>>>(feat, W1, b1, W2, b2, zbuf);
    k_loss<<<dim3(NN / 256), 256, 0, stream>>>(zbuf, FMpos, FPpos, FMtot, FPtot,
                                               cntF, cntP, out);
}